// Round 1
// baseline (450.645 us; speedup 1.0000x reference)
//
#include <hip/hip_runtime.h>

// Correlation: out[b,(di+4)*9+(dj+4),i,j] = (1/128) * sum_c f1[b,c,i,j]*f2[b,c,i+di,j+dj]
// B=8 C=128 H=128 W=256, di,dj in [-4,4], f2 zero-padded.
//
// v4: LDS-FREE via DPP halo exchange. v3 post-mortem: LDS was only a +/-1-lane
// halo shuffle (each wave read only its own staged row); VGPR_Count=48 showed the
// compiler had sunk the f1 prefetch (pipeline collapse), occupancy 25% showed a
// solo-block tail (grid = exactly 4 x 9-wave blocks per CU).
// Now: lane l holds f2 cols 4l..4l+3 in registers; window halo comes from
// v_mov_b32_dpp wave_shr:1 / wave_shl:1 with bound_ctrl:0 -> wave-edge lanes get
// ZERO, which is exactly the image-column zero padding. No LDS, no barriers, no
// staging. Waves fully independent -> 256-thread blocks, 2304 blocks (9/CU),
// __launch_bounds__(256,6) grants ~85 VGPRs so the scheduler can hoist loads.

#define CT 128
#define HH 128
#define WW 256
#define NK 81
#define HW ((size_t)HH * WW)

// lane l <- lane l-1 ; lane 0 <- 0   (DPP wave_shr:1, bound_ctrl:0)
__device__ __forceinline__ float halo_left(float x) {
    return __int_as_float(__builtin_amdgcn_update_dpp(
        0, __float_as_int(x), 0x138, 0xF, 0xF, true));
}
// lane l <- lane l+1 ; lane 63 <- 0  (DPP wave_shl:1, bound_ctrl:0)
__device__ __forceinline__ float halo_right(float x) {
    return __int_as_float(__builtin_amdgcn_update_dpp(
        0, __float_as_int(x), 0x130, 0xF, 0xF, true));
}

__global__ __launch_bounds__(256, 6)
void corr_kernel(const float* __restrict__ f1, const float* __restrict__ f2,
                 float* __restrict__ out) {
    const int l  = threadIdx.x & 63;                      // lane: cols 4l..4l+3
    const int gw = blockIdx.x * 4 + (threadIdx.x >> 6);   // global wave id 0..9215
    const int wy = gw % 9;                                // di = wy-4
    const int bi = gw / 9;                                // 0..1023
    const int i0 = bi & (HH - 1);                         // output row
    const int b  = bi >> 7;                               // batch
    const int R  = i0 - 4 + wy;                           // f2 image row

    float* op = out + ((size_t)(b * NK + wy * 9) * HH + i0) * WW + 4 * l;

    if ((unsigned)R >= (unsigned)HH) {
        // whole f2 row out of image -> 9 zero output rows, done
        const float4 z = make_float4(0.f, 0.f, 0.f, 0.f);
#pragma unroll
        for (int d = 0; d < 9; ++d) *(float4*)(op + (size_t)d * HW) = z;
        return;
    }

    const float* p1 = f1 + ((size_t)b * CT * HH + i0) * WW + 4 * l;
    const float* p2 = f2 + ((size_t)b * CT * HH + R) * WW + 4 * l;

    float acc[9][4];
#pragma unroll
    for (int d = 0; d < 9; ++d)
#pragma unroll
        for (int p = 0; p < 4; ++p) acc[d][p] = 0.f;

    // 64 chunks of 2 channels: 4x dwordx4 load, 16 DPP, 72 FMA per chunk.
    for (int q = 0; q < CT / 2; ++q) {
        const float4 a0 = *(const float4*)p1;
        const float4 a1 = *(const float4*)(p1 + HW);
        const float4 b0 = *(const float4*)p2;
        const float4 b1 = *(const float4*)(p2 + HW);
        p1 += 2 * HW;
        p2 += 2 * HW;
#pragma unroll
        for (int cc = 0; cc < 2; ++cc) {
            const float4& a = cc ? a1 : a0;
            const float4& r = cc ? b1 : b0;
            float w[12];                    // image cols 4l-4 .. 4l+7
            w[0]  = halo_left(r.x);  w[1]  = halo_left(r.y);
            w[2]  = halo_left(r.z);  w[3]  = halo_left(r.w);
            w[4]  = r.x;             w[5]  = r.y;
            w[6]  = r.z;             w[7]  = r.w;
            w[8]  = halo_right(r.x); w[9]  = halo_right(r.y);
            w[10] = halo_right(r.z); w[11] = halo_right(r.w);
            const float fv[4] = {a.x, a.y, a.z, a.w};
#pragma unroll
            for (int d = 0; d < 9; ++d)
#pragma unroll
                for (int p = 0; p < 4; ++p)
                    acc[d][p] += fv[p] * w[p + d];
        }
    }

    const float s = 1.0f / 128.0f;
#pragma unroll
    for (int d = 0; d < 9; ++d)
        *(float4*)(op + (size_t)d * HW) =
            make_float4(acc[d][0] * s, acc[d][1] * s, acc[d][2] * s, acc[d][3] * s);
}

extern "C" void kernel_launch(void* const* d_in, const int* in_sizes, int n_in,
                              void* d_out, int out_size, void* d_ws, size_t ws_size,
                              hipStream_t stream) {
    const float* f1 = (const float*)d_in[0];
    const float* f2 = (const float*)d_in[1];
    float* out = (float*)d_out;
    dim3 grid(2304);   // 9216 independent waves: 8 b x 128 i0 x 9 di
    dim3 block(256);   // 4 waves/block; 9 blocks/CU of work, ~6 resident
    hipLaunchKernelGGL(corr_kernel, grid, block, 0, stream, f1, f2, out);
}

// Round 2
// 412.374 us; speedup vs baseline: 1.0928x; 1.0928x over previous
//
#include <hip/hip_runtime.h>

// Correlation: out[b,(di+4)*9+(dj+4),i,j] = (1/128) * sum_c f1[b,c,i,j]*f2[b,c,i+di,j+dj]
// B=8 C=128 H=128 W=256, di,dj in [-4,4], f2 zero-padded.
//
// v5: v4 post-mortem showed two regressions vs theory:
//  (a) FETCH 143->616MB: independent 256-thread blocks scattered the 9 waves of
//      each (b,i0) across XCDs -> 2.36GB demand hit L3 instead of L1/L2.
//  (b) VGPR=40: compiler sank loads to use points -> 4 serial latency exposures
//      per chunk -> VALUBusy stuck at 26%.
// Fixes:
//  - 576-thread blocks again (9 waves = one (b,i0) on one CU): f1 loads are
//    IDENTICAL addresses across the 9 waves -> L1 broadcast; no LDS, DPP halo
//    (wave_shr/shl with bound_ctrl:0 gives the column zero-padding for free).
//  - XCD-chunked swizzle L=(p&7)*128+(p>>3): XCD x <-> batch x, consecutive i0
//    adjacent on the same XCD -> f2 row reuse window (1.15MB) lives in that L2.
//  - 4-channel chunks: 8 independent global_load_dwordx4 batched, ONE vmcnt wait
//    per 176 VALU ops; sched_barrier(0) after the load cluster stops re-sinking.
//  - __launch_bounds__(576,4): ~128 VGPR budget so 8 float4 stay in flight.
//    2 blocks/CU resident, grid 1024 = exactly 2 rounds, no straggler tail.

#define CT 128
#define HH 128
#define WW 256
#define NK 81
#define HW ((size_t)HH * WW)

// lane l <- lane l-1 ; lane 0 <- 0   (DPP wave_shr:1, bound_ctrl:0) [verified v4]
__device__ __forceinline__ float halo_left(float x) {
    return __int_as_float(__builtin_amdgcn_update_dpp(
        0, __float_as_int(x), 0x138, 0xF, 0xF, true));
}
// lane l <- lane l+1 ; lane 63 <- 0  (DPP wave_shl:1, bound_ctrl:0) [verified v4]
__device__ __forceinline__ float halo_right(float x) {
    return __int_as_float(__builtin_amdgcn_update_dpp(
        0, __float_as_int(x), 0x130, 0xF, 0xF, true));
}

__global__ __launch_bounds__(576, 4)
void corr_kernel(const float* __restrict__ f1, const float* __restrict__ f2,
                 float* __restrict__ out) {
    const int l  = threadIdx.x;            // 0..63, lane owns cols 4l..4l+3
    const int wy = threadIdx.y;            // 0..8 -> di = wy-4
    const int p  = blockIdx.x;
    const int L  = ((p & 7) << 7) | (p >> 3);  // XCD-chunked: XCD = batch
    const int b  = L >> 7;                 // batch 0..7
    const int i0 = L & 127;                // output row
    const int R  = i0 - 4 + wy;            // f2 image row this wave reads

    float* op = out + ((size_t)(b * NK + wy * 9) * HH + i0) * WW + 4 * l;

    if ((unsigned)R >= (unsigned)HH) {
        const float4 z = make_float4(0.f, 0.f, 0.f, 0.f);
#pragma unroll
        for (int d = 0; d < 9; ++d) *(float4*)(op + (size_t)d * HW) = z;
        return;
    }

    const float* p1 = f1 + ((size_t)b * CT * HH + i0) * WW + 4 * l;
    const float* p2 = f2 + ((size_t)b * CT * HH + R) * WW + 4 * l;

    float acc[9][4];
#pragma unroll
    for (int d = 0; d < 9; ++d)
#pragma unroll
        for (int q = 0; q < 4; ++q) acc[d][q] = 0.f;

    // 32 chunks of 4 channels: 8 batched dwordx4 loads, then 32 DPP + 144 FMA.
    for (int q = 0; q < CT / 4; ++q) {
        float4 A[4], B[4];
#pragma unroll
        for (int cc = 0; cc < 4; ++cc) {
            A[cc] = *(const float4*)(p1 + (size_t)cc * HW);
            B[cc] = *(const float4*)(p2 + (size_t)cc * HW);
        }
        p1 += 4 * HW;
        p2 += 4 * HW;
        // keep the 8 loads clustered ahead of all uses: one wait per chunk
        __builtin_amdgcn_sched_barrier(0);
#pragma unroll
        for (int cc = 0; cc < 4; ++cc) {
            const float4& a = A[cc];
            const float4& r = B[cc];
            float w[12];                    // image cols 4l-4 .. 4l+7
            w[0]  = halo_left(r.x);  w[1]  = halo_left(r.y);
            w[2]  = halo_left(r.z);  w[3]  = halo_left(r.w);
            w[4]  = r.x;             w[5]  = r.y;
            w[6]  = r.z;             w[7]  = r.w;
            w[8]  = halo_right(r.x); w[9]  = halo_right(r.y);
            w[10] = halo_right(r.z); w[11] = halo_right(r.w);
            const float fv[4] = {a.x, a.y, a.z, a.w};
#pragma unroll
            for (int d = 0; d < 9; ++d)
#pragma unroll
                for (int t = 0; t < 4; ++t)
                    acc[d][t] += fv[t] * w[t + d];
        }
    }

    const float s = 1.0f / 128.0f;
#pragma unroll
    for (int d = 0; d < 9; ++d)
        *(float4*)(op + (size_t)d * HW) =
            make_float4(acc[d][0] * s, acc[d][1] * s, acc[d][2] * s, acc[d][3] * s);
}

extern "C" void kernel_launch(void* const* d_in, const int* in_sizes, int n_in,
                              void* d_out, int out_size, void* d_ws, size_t ws_size,
                              hipStream_t stream) {
    const float* f1 = (const float*)d_in[0];
    const float* f2 = (const float*)d_in[1];
    float* out = (float*)d_out;
    dim3 grid(1024);       // one block per (b, i0); swizzled to XCD = batch
    dim3 block(64, 9);     // 9 waves: one per di, no barriers, no LDS
    hipLaunchKernelGGL(corr_kernel, grid, block, 0, stream, f1, f2, out);
}